// Round 4
// baseline (519.253 us; speedup 1.0000x reference)
//
#include <hip/hip_runtime.h>
#include <hip/hip_bf16.h>
#include <stdint.h>

// Problem: B=2, S=2048, D=2048, H=16, HD=128
#define S_ 2048
#define D_ 2048
#define H_ 16
#define HD_ 128

typedef __bf16 bf16x8 __attribute__((ext_vector_type(8)));
typedef float f32x4 __attribute__((ext_vector_type(4)));
typedef unsigned short ushort_t;
typedef ushort_t us4 __attribute__((ext_vector_type(4)));

__device__ __forceinline__ float bf2f(ushort_t u) {
  union { float f; uint32_t i; } x; x.i = ((uint32_t)u) << 16; return x.f;
}
__device__ __forceinline__ ushort_t f2bf(float f) {
  union { float f; uint32_t i; } x; x.f = f;
  uint32_t r = x.i + 0x7fffu + ((x.i >> 16) & 1u);  // RNE
  return (ushort_t)(r >> 16);
}

// async global->LDS, 16B per lane. LDS dest is wave-uniform base + lane*16.
__device__ __forceinline__ void async_copy16(const void* g, void* l) {
  __builtin_amdgcn_global_load_lds(
      (const __attribute__((address_space(1))) unsigned int*)g,
      (__attribute__((address_space(3))) unsigned int*)l, 16, 0, 0);
}

__device__ __forceinline__ void store_val(float* p, float v) { *p = v; }
__device__ __forceinline__ void store_val(ushort_t* p, float v) { *p = f2bf(v); }

// ---------------- fp32 -> bf16 convert (vectorized x4) ----------------
__global__ __launch_bounds__(256) void cvt_f32_bf16(const float* __restrict__ in,
                                                    ushort_t* __restrict__ out,
                                                    int n4) {
  int i = blockIdx.x * 256 + threadIdx.x;
  if (i >= n4) return;
  const float4 v = ((const float4*)in)[i];
  us4 o;
  o.x = f2bf(v.x); o.y = f2bf(v.y); o.z = f2bf(v.z); o.w = f2bf(v.w);
  ((us4*)out)[i] = o;
}

// ---------------- GEMM: C[M,N] = A[M,K] * B[N,K]^T  (bf16, fp32 acc) --------
// 128x128 tile, BK=32, conflict-free LDS: row stride 40 shorts (80 B):
// bank start = row*20 mod 32 -> 8 distinct starts x2 lanes = 2-way (free).
// Staged via global_load_lds w=16: slot = row*5 + chunk, chunk 4 = pad
// (sourced from the row's chunk 0 - same cache line, never read back).
// ATOMIC epilogue enables split-K via blockIdx.z.
#define GPAD 40  // shorts per LDS row
template <typename OutT, bool ATOMIC>
__global__ __launch_bounds__(256) void gemm_bt(const ushort_t* __restrict__ A,
                                               const ushort_t* __restrict__ Bm,
                                               OutT* __restrict__ C,
                                               int M, int N, int K, int ksplit) {
  __shared__ __align__(16) ushort_t As[128 * GPAD + 256];  // +512 B overflow pad
  __shared__ __align__(16) ushort_t Bs[128 * GPAD + 256];
  const int tid = threadIdx.x;
  const int wave = tid >> 6, lane = tid & 63;
  const int quad = lane >> 4, l16 = lane & 15;
  const int bm = blockIdx.y * 128, bn = blockIdx.x * 128;
  const int wm = (wave >> 1) * 64, wn = (wave & 1) * 64;
  const int kbeg = blockIdx.z * ksplit, kend = kbeg + ksplit;

  f32x4 acc[4][4] = {};

  // staging: 640 slots of 16 B per buffer; wave w covers slots [160w,160w+192)
  // (tail 32 overlap next wave's head with identical bytes - benign)
  const int w160 = wave * 160;
  const ushort_t* gAp[3];
  const ushort_t* gBp[3];
  ushort_t* ldsA[3];
  ushort_t* ldsB[3];
#pragma unroll
  for (int i = 0; i < 3; ++i) {
    int s = w160 + i * 64 + lane;
    int r = s / 5, c = s % 5;
    if (r > 127) r = 127;          // overflow slots: safe addr, data unused
    int sc = (c == 4) ? 0 : c;     // pad chunk sources chunk 0 (same line)
    gAp[i] = A + (size_t)(bm + r) * K + sc * 8;
    gBp[i] = Bm + (size_t)(bn + r) * K + sc * 8;
    ldsA[i] = As + (w160 + i * 64) * 8;
    ldsB[i] = Bs + (w160 + i * 64) * 8;
  }

  for (int k0 = kbeg; k0 < kend; k0 += 32) {
    __syncthreads();
#pragma unroll
    for (int i = 0; i < 3; ++i) async_copy16(gAp[i] + k0, ldsA[i]);
#pragma unroll
    for (int i = 0; i < 3; ++i) async_copy16(gBp[i] + k0, ldsB[i]);
    __syncthreads();
    bf16x8 af[4], bfr[4];
#pragma unroll
    for (int i = 0; i < 4; ++i)
      af[i] = *(const bf16x8*)(As + (wm + i * 16 + l16) * GPAD + quad * 8);
#pragma unroll
    for (int i = 0; i < 4; ++i)
      bfr[i] = *(const bf16x8*)(Bs + (wn + i * 16 + l16) * GPAD + quad * 8);
#pragma unroll
    for (int mi = 0; mi < 4; ++mi)
#pragma unroll
      for (int ni = 0; ni < 4; ++ni)
        acc[mi][ni] = __builtin_amdgcn_mfma_f32_16x16x32_bf16(af[mi], bfr[ni],
                                                              acc[mi][ni], 0, 0, 0);
  }
#pragma unroll
  for (int mi = 0; mi < 4; ++mi)
#pragma unroll
    for (int ni = 0; ni < 4; ++ni)
#pragma unroll
      for (int r = 0; r < 4; ++r) {
        int row = bm + wm + mi * 16 + quad * 4 + r;
        int col = bn + wn + ni * 16 + l16;
        if constexpr (ATOMIC)
          unsafeAtomicAdd((float*)&C[(size_t)row * N + col], acc[mi][ni][r]);
        else
          store_val(&C[(size_t)row * N + col], acc[mi][ni][r]);
      }
}

// ---------------- RoPE in-place on q and k halves of qkv ----------------
__global__ __launch_bounds__(256) void rope_k(ushort_t* __restrict__ qkv,
                                              const float* __restrict__ fc,
                                              const float* __restrict__ fs) {
  int idx = blockIdx.x * 256 + threadIdx.x;
  int i = idx & 63;
  int hh = (idx >> 6) & 15;
  int m = idx >> 10;
  int s = m & (S_ - 1);
  float c = fc[s * 64 + i], sn = fs[s * 64 + i];
  size_t off = (size_t)m * (3 * D_) + hh * HD_ + 2 * i;
#pragma unroll
  for (int part = 0; part < 2; ++part) {
    uint32_t* p = (uint32_t*)(qkv + off + part * D_);
    uint32_t v = *p;
    float re = bf2f((ushort_t)(v & 0xffffu));
    float im = bf2f((ushort_t)(v >> 16));
    float nr = re * c - im * sn;
    float ni = re * sn + im * c;
    *p = (uint32_t)f2bf(nr) | ((uint32_t)f2bf(ni) << 16);
  }
}

// ---------------- V transpose: qkv V part -> VTg[(b*H+h)*HD + d][S] ---------
__global__ __launch_bounds__(256) void vt_prep(const ushort_t* __restrict__ qkv,
                                               ushort_t* __restrict__ VTg) {
  __shared__ __align__(16) ushort_t T[64 * 136];
  const int st = blockIdx.x, h = blockIdx.y, b = blockIdx.z;
  const int tid = threadIdx.x;
  const ushort_t* gV = qkv + (size_t)(b * S_ + st * 64) * (3 * D_) + 2 * D_ + h * HD_;
  {
    const int r = tid >> 2, cc = (tid & 3) * 32;
    const ushort_t* src = gV + (size_t)r * (3 * D_) + cc;
    uint4 a0 = ((const uint4*)src)[0];
    uint4 a1 = ((const uint4*)src)[1];
    uint4 a2 = ((const uint4*)src)[2];
    uint4 a3 = ((const uint4*)src)[3];
    ushort_t* dst = T + r * 136 + cc;
    ((uint4*)dst)[0] = a0; ((uint4*)dst)[1] = a1;
    ((uint4*)dst)[2] = a2; ((uint4*)dst)[3] = a3;
  }
  __syncthreads();
  const int d = tid >> 1, kh = (tid & 1) * 32;
  ushort_t buf[32];
#pragma unroll
  for (int j = 0; j < 32; ++j) buf[j] = T[(kh + j) * 136 + d];
  ushort_t* out = VTg + ((size_t)((b * H_ + h) * HD_ + d)) * S_ + st * 64 + kh;
  ((uint4*)out)[0] = *(const uint4*)(buf + 0);
  ((uint4*)out)[1] = *(const uint4*)(buf + 8);
  ((uint4*)out)[2] = *(const uint4*)(buf + 16);
  ((uint4*)out)[3] = *(const uint4*)(buf + 24);
}

// ---------------- Flash attention v3: key-split chunks, async staging -------
#define SOFTMAX_C 12.0f

__global__ __launch_bounds__(256, 4) void attn_fwd(const ushort_t* __restrict__ qkv,
                                                   const ushort_t* __restrict__ VTg,
                                                   float* __restrict__ Oacc,
                                                   float* __restrict__ lsum_g) {
  __shared__ __align__(16) ushort_t Kl[64 * 128];   // [key][d]   16 KB
  __shared__ __align__(16) ushort_t VT[128 * 64];   // [d][key]   16 KB
  __shared__ __align__(16) ushort_t Pl[4 * 16 * 64];// per-wave P  8 KB

  const int j = 79 - (int)blockIdx.x;
  int qt, c;
  if (j < 8)       { qt = j;                 c = 0; }
  else if (j < 24) { int t = j - 8;  qt = 8 + (t >> 1);  c = t & 1; }
  else if (j < 48) { int t = j - 24; qt = 16 + t / 3;    c = t % 3; }
  else             { int t = j - 48; qt = 24 + (t >> 2); c = t & 3; }
  const int h = blockIdx.y, b = blockIdx.z;
  const int kt0 = c * 8;
  const int kt_end = min(kt0 + 8, qt + 1);

  const int tid = threadIdx.x;
  const int wave = tid >> 6, lane = tid & 63;
  const int quad = lane >> 4, l16 = lane & 15;
  const float scale = 0.08838834764831845f;  // 1/sqrt(128)

  const int qg = qt * 64 + wave * 16 + l16;
  const ushort_t* qrow = qkv + (size_t)(b * S_ + qg) * (3 * D_) + h * HD_;
  bf16x8 qf[4];
#pragma unroll
  for (int cc = 0; cc < 4; ++cc)
    qf[cc] = *(const bf16x8*)(qrow + cc * 32 + quad * 8);

  f32x4 o[8] = {};
  float lsum[4] = {0.f, 0.f, 0.f, 0.f};
  const int q_row_base = qt * 64 + wave * 16 + quad * 4;
  ushort_t* Pw = Pl + wave * 16 * 64;

  const ushort_t* gK = qkv + (size_t)(b * S_) * (3 * D_) + D_ + h * HD_;
  const ushort_t* gVT = VTg + (size_t)(b * H_ + h) * HD_ * S_;

  const int krow_off = lane >> 4;
  const int kchunk = lane & 15;
  const int vrow_off = lane >> 3;
  const int vchunk = lane & 7;

  for (int kt = kt0; kt < kt_end; ++kt) {
    __syncthreads();
#pragma unroll
    for (int i = 0; i < 4; ++i) {
      int row = wave * 16 + i * 4 + krow_off;
      int lchunk = kchunk ^ (row & 15);
      async_copy16(gK + (size_t)(kt * 64 + row) * (3 * D_) + lchunk * 8,
                   Kl + (wave * 16 + i * 4) * 128);
    }
#pragma unroll
    for (int i = 0; i < 4; ++i) {
      int row = wave * 32 + i * 8 + vrow_off;
      int lchunk = vchunk ^ (row & 7);
      async_copy16(gVT + (size_t)row * S_ + kt * 64 + lchunk * 8,
                   VT + (wave * 32 + i * 8) * 64);
    }
    __syncthreads();

    const bool diag = (kt == qt);
#pragma unroll
    for (int g = 0; g < 4; ++g) {
      f32x4 s = {0.f, 0.f, 0.f, 0.f};
#pragma unroll
      for (int cc = 0; cc < 4; ++cc) {
        bf16x8 kf = *(const bf16x8*)(Kl + (g * 16 + l16) * 128 +
                                     (((cc * 4 + quad) ^ l16) * 8));
        s = __builtin_amdgcn_mfma_f32_16x16x32_bf16(qf[cc], kf, s, 0, 0, 0);
      }
      const int key = kt * 64 + g * 16 + l16;
#pragma unroll
      for (int r = 0; r < 4; ++r) {
        float e = __expf(s[r] * scale - SOFTMAX_C);
        float p = (!diag || key <= q_row_base + r) ? e : 0.f;
        lsum[r] += p;
        int prow = quad * 4 + r;
        int pcol = g * 16 + l16;
        Pw[prow * 64 + (((pcol >> 3) ^ (prow & 7)) * 8) + (pcol & 7)] = f2bf(p);
      }
    }
    bf16x8 pf0 = *(const bf16x8*)(Pw + l16 * 64 + ((quad ^ (l16 & 7)) * 8));
    bf16x8 pf1 = *(const bf16x8*)(Pw + l16 * 64 + (((4 + quad) ^ (l16 & 7)) * 8));
#pragma unroll
    for (int dc = 0; dc < 8; ++dc) {
      bf16x8 v0 = *(const bf16x8*)(VT + (dc * 16 + l16) * 64 +
                                   (((0 * 4 + quad) ^ (l16 & 7)) * 8));
      o[dc] = __builtin_amdgcn_mfma_f32_16x16x32_bf16(pf0, v0, o[dc], 0, 0, 0);
      bf16x8 v1 = *(const bf16x8*)(VT + (dc * 16 + l16) * 64 +
                                   (((1 * 4 + quad) ^ (l16 & 7)) * 8));
      o[dc] = __builtin_amdgcn_mfma_f32_16x16x32_bf16(pf1, v1, o[dc], 0, 0, 0);
    }
  }

#pragma unroll
  for (int r = 0; r < 4; ++r) {
    float l = lsum[r];
    l += __shfl_xor(l, 1, 64);
    l += __shfl_xor(l, 2, 64);
    l += __shfl_xor(l, 4, 64);
    l += __shfl_xor(l, 8, 64);
    size_t row = (size_t)(b * S_ + q_row_base + r);
    if (l16 == 0) unsafeAtomicAdd(&lsum_g[row * H_ + h], l);
#pragma unroll
    for (int dc = 0; dc < 8; ++dc)
      unsafeAtomicAdd(&Oacc[row * D_ + h * HD_ + dc * 16 + l16], o[dc][r]);
  }
}

// ---------------- combine: normalize O by lsum, emit bf16 -------------------
__global__ __launch_bounds__(256) void combine(const float* __restrict__ Oacc,
                                               const float* __restrict__ lsum_g,
                                               ushort_t* __restrict__ attn) {
  int i = blockIdx.x * 256 + threadIdx.x;
  float4 v = ((const float4*)Oacc)[i];
  int flat = i * 4;
  int row = flat >> 11;
  int h = (flat >> 7) & 15;
  float inv = 1.0f / lsum_g[row * H_ + h];
  us4 o;
  o.x = f2bf(v.x * inv); o.y = f2bf(v.y * inv);
  o.z = f2bf(v.z * inv); o.w = f2bf(v.w * inv);
  ((us4*)attn)[i] = o;
}

// ---------------- launch ----------------
extern "C" void kernel_launch(void* const* d_in, const int* in_sizes, int n_in,
                              void* d_out, int out_size, void* d_ws, size_t ws_size,
                              hipStream_t stream) {
  const float* x = (const float*)d_in[0];
  const float* w_qkv = (const float*)d_in[1];
  const float* w_out = (const float*)d_in[2];
  const float* fcos = (const float*)d_in[3];
  const float* fsin = (const float*)d_in[4];
  float* out = (float*)d_out;

  char* ws = (char*)d_ws;
  ushort_t* x_bf    = (ushort_t*)(ws + 0);
  ushort_t* wqkv_bf = (ushort_t*)(ws + 16777216);
  ushort_t* wout_bf = (ushort_t*)(ws + 41943040);
  ushort_t* qkv     = (ushort_t*)(ws + 50331648);
  ushort_t* attn    = (ushort_t*)(ws + 100663296);
  float* Oacc   = (float*)(ws + 0);
  float* lsum_g = (float*)(ws + 33554432);
  ushort_t* VTg = (ushort_t*)(ws + 100663296);

  // zero the fp32 output accumulator for split-K atomics (d_out is poisoned)
  hipMemsetAsync(out, 0, 33554432, stream);

  cvt_f32_bf16<<<8192, 256, 0, stream>>>(x, x_bf, 2097152);
  cvt_f32_bf16<<<12288, 256, 0, stream>>>(w_qkv, wqkv_bf, 3145728);
  cvt_f32_bf16<<<4096, 256, 0, stream>>>(w_out, wout_bf, 1048576);

  // qkv = x @ w_qkv^T : M=4096, N=6144, K=2048
  gemm_bt<ushort_t, false><<<dim3(48, 32, 1), 256, 0, stream>>>(
      x_bf, wqkv_bf, qkv, 4096, 6144, 2048, 2048);
  rope_k<<<16384, 256, 0, stream>>>(qkv, fcos, fsin);
  vt_prep<<<dim3(32, 16, 2), 256, 0, stream>>>(qkv, VTg);

  hipMemsetAsync(Oacc, 0, 33554432, stream);
  hipMemsetAsync(lsum_g, 0, 262144, stream);

  attn_fwd<<<dim3(80, 16, 2), 256, 0, stream>>>(qkv, VTg, Oacc, lsum_g);
  combine<<<8192, 256, 0, stream>>>(Oacc, lsum_g, attn);

  // out = attn @ w_out^T : M=4096, N=2048, K=2048, split-K=2, fp32 atomic out
  gemm_bt<float, true><<<dim3(16, 32, 2), 256, 0, stream>>>(
      attn, wout_bf, out, 4096, 2048, 2048, 1024);
}

// Round 5
// 515.853 us; speedup vs baseline: 1.0066x; 1.0066x over previous
//
#include <hip/hip_runtime.h>
#include <hip/hip_bf16.h>
#include <stdint.h>

// Problem: B=2, S=2048, D=2048, H=16, HD=128
#define S_ 2048
#define D_ 2048
#define H_ 16
#define HD_ 128

typedef __bf16 bf16x8 __attribute__((ext_vector_type(8)));
typedef float f32x4 __attribute__((ext_vector_type(4)));
typedef unsigned short ushort_t;
typedef ushort_t us4 __attribute__((ext_vector_type(4)));

__device__ __forceinline__ float bf2f(ushort_t u) {
  union { float f; uint32_t i; } x; x.i = ((uint32_t)u) << 16; return x.f;
}
__device__ __forceinline__ ushort_t f2bf(float f) {
  union { float f; uint32_t i; } x; x.f = f;
  uint32_t r = x.i + 0x7fffu + ((x.i >> 16) & 1u);  // RNE
  return (ushort_t)(r >> 16);
}

// async global->LDS, 16B per lane. LDS dest is wave-uniform base + lane*16.
__device__ __forceinline__ void async_copy16(const void* g, void* l) {
  __builtin_amdgcn_global_load_lds(
      (const __attribute__((address_space(1))) unsigned int*)g,
      (__attribute__((address_space(3))) unsigned int*)l, 16, 0, 0);
}

__device__ __forceinline__ void store_val(float* p, float v) { *p = v; }
__device__ __forceinline__ void store_val(ushort_t* p, float v) { *p = f2bf(v); }

// ---------------- fp32 -> bf16 convert, all three tensors in one launch -----
// dst regions are contiguous: x_bf [0,2097152) f4, wqkv [..,5242880), wout rest
__global__ __launch_bounds__(256) void cvt_all(const float* __restrict__ x,
                                               const float* __restrict__ wqkv,
                                               const float* __restrict__ wout,
                                               ushort_t* __restrict__ dst) {
  int i = blockIdx.x * 256 + threadIdx.x;  // [0, 6291456)
  const float4 v = (i < 2097152) ? ((const float4*)x)[i]
                 : (i < 5242880) ? ((const float4*)wqkv)[i - 2097152]
                                 : ((const float4*)wout)[i - 5242880];
  us4 o;
  o.x = f2bf(v.x); o.y = f2bf(v.y); o.z = f2bf(v.z); o.w = f2bf(v.w);
  ((us4*)dst)[i] = o;
}

// ---------------- GEMM: C[M,N] = A[M,K] * B[N,K]^T  (bf16, fp32 acc) --------
// m97/R3 structure: 128x128 tile, BK=32, 4 waves 2x2, global_load_lds w=16.
// ATOMIC: fp32 atomic-add epilogue (split-K via blockIdx.z).
// ROPE: apply rotary embedding in the epilogue for cols < 2*D_ (q,k regions).
template <typename OutT, bool ATOMIC, bool ROPE>
__global__ __launch_bounds__(256) void gemm_bt(const ushort_t* __restrict__ A,
                                               const ushort_t* __restrict__ Bm,
                                               OutT* __restrict__ C,
                                               int M, int N, int K, int ksplit,
                                               const float* __restrict__ fc,
                                               const float* __restrict__ fs) {
  __shared__ __align__(16) ushort_t As[128 * 32];
  __shared__ __align__(16) ushort_t Bs[128 * 32];
  const int tid = threadIdx.x;
  const int wave = tid >> 6, lane = tid & 63;
  const int quad = lane >> 4, l16 = lane & 15;
  const int bm = blockIdx.y * 128, bn = blockIdx.x * 128;
  const int wm = (wave >> 1) * 64, wn = (wave & 1) * 64;
  const int kbeg = blockIdx.z * ksplit, kend = kbeg + ksplit;

  f32x4 acc[4][4] = {};

  const int c0 = wave * 2, c1 = c0 + 1;
  const int srow = lane >> 2;
  const int scol = (lane & 3) * 8;
  const ushort_t* gA0 = A + (size_t)(bm + c0 * 16 + srow) * K + scol;
  const ushort_t* gA1 = A + (size_t)(bm + c1 * 16 + srow) * K + scol;
  const ushort_t* gB0 = Bm + (size_t)(bn + c0 * 16 + srow) * K + scol;
  const ushort_t* gB1 = Bm + (size_t)(bn + c1 * 16 + srow) * K + scol;
  ushort_t* lA0 = As + c0 * 512;
  ushort_t* lA1 = As + c1 * 512;
  ushort_t* lB0 = Bs + c0 * 512;
  ushort_t* lB1 = Bs + c1 * 512;

  for (int k0 = kbeg; k0 < kend; k0 += 32) {
    __syncthreads();
    async_copy16(gA0 + k0, lA0);
    async_copy16(gA1 + k0, lA1);
    async_copy16(gB0 + k0, lB0);
    async_copy16(gB1 + k0, lB1);
    __syncthreads();
    bf16x8 af[4], bfr[4];
#pragma unroll
    for (int i = 0; i < 4; ++i)
      af[i] = *(const bf16x8*)(As + (wm + i * 16 + l16) * 32 + quad * 8);
#pragma unroll
    for (int i = 0; i < 4; ++i)
      bfr[i] = *(const bf16x8*)(Bs + (wn + i * 16 + l16) * 32 + quad * 8);
#pragma unroll
    for (int mi = 0; mi < 4; ++mi)
#pragma unroll
      for (int ni = 0; ni < 4; ++ni)
        acc[mi][ni] = __builtin_amdgcn_mfma_f32_16x16x32_bf16(af[mi], bfr[ni],
                                                              acc[mi][ni], 0, 0, 0);
  }
  // epilogue: C/D layout col=lane&15, row=quad*4+reg
  const bool do_rope = ROPE && (bn < 2 * D_);
#pragma unroll
  for (int mi = 0; mi < 4; ++mi)
#pragma unroll
    for (int ni = 0; ni < 4; ++ni) {
      const int col = bn + wn + ni * 16 + l16;
#pragma unroll
      for (int r = 0; r < 4; ++r) {
        const int row = bm + wm + mi * 16 + quad * 4 + r;
        float v = acc[mi][ni][r];
        if (do_rope) {
          // pair (2i,2i+1) lives in adjacent l16 lanes; swap via shfl_xor
          const int s = row & (S_ - 1);
          const int fi = (col >> 1) & 63;
          const float c = fc[s * 64 + fi];
          const float sn = fs[s * 64 + fi];
          const float other = __shfl_xor(v, 1, 64);
          v = (col & 1) ? (other * sn + v * c)   // im' = re*sin + im*cos
                        : (v * c - other * sn);  // re' = re*cos - im*sin
        }
        if constexpr (ATOMIC)
          unsafeAtomicAdd((float*)&C[(size_t)row * N + col], v);
        else
          store_val(&C[(size_t)row * N + col], v);
      }
    }
}

// ---------------- V transpose: qkv V part -> VTg[(b*H+h)*HD + d][S] ---------
__global__ __launch_bounds__(256) void vt_prep(const ushort_t* __restrict__ qkv,
                                               ushort_t* __restrict__ VTg) {
  __shared__ __align__(16) ushort_t T[64 * 136];
  const int st = blockIdx.x, h = blockIdx.y, b = blockIdx.z;
  const int tid = threadIdx.x;
  const ushort_t* gV = qkv + (size_t)(b * S_ + st * 64) * (3 * D_) + 2 * D_ + h * HD_;
  {
    const int r = tid >> 2, cc = (tid & 3) * 32;
    const ushort_t* src = gV + (size_t)r * (3 * D_) + cc;
    uint4 a0 = ((const uint4*)src)[0];
    uint4 a1 = ((const uint4*)src)[1];
    uint4 a2 = ((const uint4*)src)[2];
    uint4 a3 = ((const uint4*)src)[3];
    ushort_t* dst = T + r * 136 + cc;
    ((uint4*)dst)[0] = a0; ((uint4*)dst)[1] = a1;
    ((uint4*)dst)[2] = a2; ((uint4*)dst)[3] = a3;
  }
  __syncthreads();
  const int d = tid >> 1, kh = (tid & 1) * 32;
  ushort_t buf[32];
#pragma unroll
  for (int j = 0; j < 32; ++j) buf[j] = T[(kh + j) * 136 + d];
  ushort_t* out = VTg + ((size_t)((b * H_ + h) * HD_ + d)) * S_ + st * 64 + kh;
  ((uint4*)out)[0] = *(const uint4*)(buf + 0);
  ((uint4*)out)[1] = *(const uint4*)(buf + 8);
  ((uint4*)out)[2] = *(const uint4*)(buf + 16);
  ((uint4*)out)[3] = *(const uint4*)(buf + 24);
}

// ---------------- Flash attention v3: key-split chunks, async staging -------
#define SOFTMAX_C 12.0f

__global__ __launch_bounds__(256, 4) void attn_fwd(const ushort_t* __restrict__ qkv,
                                                   const ushort_t* __restrict__ VTg,
                                                   float* __restrict__ Oacc,
                                                   float* __restrict__ lsum_g) {
  __shared__ __align__(16) ushort_t Kl[64 * 128];   // [key][d]   16 KB
  __shared__ __align__(16) ushort_t VT[128 * 64];   // [d][key]   16 KB
  __shared__ __align__(16) ushort_t Pl[4 * 16 * 64];// per-wave P  8 KB

  const int j = 79 - (int)blockIdx.x;
  int qt, c;
  if (j < 8)       { qt = j;                 c = 0; }
  else if (j < 24) { int t = j - 8;  qt = 8 + (t >> 1);  c = t & 1; }
  else if (j < 48) { int t = j - 24; qt = 16 + t / 3;    c = t % 3; }
  else             { int t = j - 48; qt = 24 + (t >> 2); c = t & 3; }
  const int h = blockIdx.y, b = blockIdx.z;
  const int kt0 = c * 8;
  const int kt_end = min(kt0 + 8, qt + 1);

  const int tid = threadIdx.x;
  const int wave = tid >> 6, lane = tid & 63;
  const int quad = lane >> 4, l16 = lane & 15;
  const float scale = 0.08838834764831845f;  // 1/sqrt(128)

  const int qg = qt * 64 + wave * 16 + l16;
  const ushort_t* qrow = qkv + (size_t)(b * S_ + qg) * (3 * D_) + h * HD_;
  bf16x8 qf[4];
#pragma unroll
  for (int cc = 0; cc < 4; ++cc)
    qf[cc] = *(const bf16x8*)(qrow + cc * 32 + quad * 8);

  f32x4 o[8] = {};
  float lsum[4] = {0.f, 0.f, 0.f, 0.f};
  const int q_row_base = qt * 64 + wave * 16 + quad * 4;
  ushort_t* Pw = Pl + wave * 16 * 64;

  const ushort_t* gK = qkv + (size_t)(b * S_) * (3 * D_) + D_ + h * HD_;
  const ushort_t* gVT = VTg + (size_t)(b * H_ + h) * HD_ * S_;

  const int krow_off = lane >> 4;
  const int kchunk = lane & 15;
  const int vrow_off = lane >> 3;
  const int vchunk = lane & 7;

  for (int kt = kt0; kt < kt_end; ++kt) {
    __syncthreads();
#pragma unroll
    for (int i = 0; i < 4; ++i) {
      int row = wave * 16 + i * 4 + krow_off;
      int lchunk = kchunk ^ (row & 15);
      async_copy16(gK + (size_t)(kt * 64 + row) * (3 * D_) + lchunk * 8,
                   Kl + (wave * 16 + i * 4) * 128);
    }
#pragma unroll
    for (int i = 0; i < 4; ++i) {
      int row = wave * 32 + i * 8 + vrow_off;
      int lchunk = vchunk ^ (row & 7);
      async_copy16(gVT + (size_t)row * S_ + kt * 64 + lchunk * 8,
                   VT + (wave * 32 + i * 8) * 64);
    }
    __syncthreads();

    const bool diag = (kt == qt);
#pragma unroll
    for (int g = 0; g < 4; ++g) {
      f32x4 s = {0.f, 0.f, 0.f, 0.f};
#pragma unroll
      for (int cc = 0; cc < 4; ++cc) {
        bf16x8 kf = *(const bf16x8*)(Kl + (g * 16 + l16) * 128 +
                                     (((cc * 4 + quad) ^ l16) * 8));
        s = __builtin_amdgcn_mfma_f32_16x16x32_bf16(qf[cc], kf, s, 0, 0, 0);
      }
      const int key = kt * 64 + g * 16 + l16;
#pragma unroll
      for (int r = 0; r < 4; ++r) {
        float e = __expf(s[r] * scale - SOFTMAX_C);
        float p = (!diag || key <= q_row_base + r) ? e : 0.f;
        lsum[r] += p;
        int prow = quad * 4 + r;
        int pcol = g * 16 + l16;
        Pw[prow * 64 + (((pcol >> 3) ^ (prow & 7)) * 8) + (pcol & 7)] = f2bf(p);
      }
    }
    bf16x8 pf0 = *(const bf16x8*)(Pw + l16 * 64 + ((quad ^ (l16 & 7)) * 8));
    bf16x8 pf1 = *(const bf16x8*)(Pw + l16 * 64 + (((4 + quad) ^ (l16 & 7)) * 8));
#pragma unroll
    for (int dc = 0; dc < 8; ++dc) {
      bf16x8 v0 = *(const bf16x8*)(VT + (dc * 16 + l16) * 64 +
                                   (((0 * 4 + quad) ^ (l16 & 7)) * 8));
      o[dc] = __builtin_amdgcn_mfma_f32_16x16x32_bf16(pf0, v0, o[dc], 0, 0, 0);
      bf16x8 v1 = *(const bf16x8*)(VT + (dc * 16 + l16) * 64 +
                                   (((1 * 4 + quad) ^ (l16 & 7)) * 8));
      o[dc] = __builtin_amdgcn_mfma_f32_16x16x32_bf16(pf1, v1, o[dc], 0, 0, 0);
    }
  }

#pragma unroll
  for (int r = 0; r < 4; ++r) {
    float l = lsum[r];
    l += __shfl_xor(l, 1, 64);
    l += __shfl_xor(l, 2, 64);
    l += __shfl_xor(l, 4, 64);
    l += __shfl_xor(l, 8, 64);
    size_t row = (size_t)(b * S_ + q_row_base + r);
    if (l16 == 0) unsafeAtomicAdd(&lsum_g[row * H_ + h], l);
#pragma unroll
    for (int dc = 0; dc < 8; ++dc)
      unsafeAtomicAdd(&Oacc[row * D_ + h * HD_ + dc * 16 + l16], o[dc][r]);
  }
}

// ---------------- combine: normalize O by lsum, emit bf16 -------------------
__global__ __launch_bounds__(256) void combine(const float* __restrict__ Oacc,
                                               const float* __restrict__ lsum_g,
                                               ushort_t* __restrict__ attn) {
  int i = blockIdx.x * 256 + threadIdx.x;
  float4 v = ((const float4*)Oacc)[i];
  int flat = i * 4;
  int row = flat >> 11;
  int h = (flat >> 7) & 15;
  float inv = 1.0f / lsum_g[row * H_ + h];
  us4 o;
  o.x = f2bf(v.x * inv); o.y = f2bf(v.y * inv);
  o.z = f2bf(v.z * inv); o.w = f2bf(v.w * inv);
  ((us4*)attn)[i] = o;
}

// ---------------- launch ----------------
extern "C" void kernel_launch(void* const* d_in, const int* in_sizes, int n_in,
                              void* d_out, int out_size, void* d_ws, size_t ws_size,
                              hipStream_t stream) {
  const float* x = (const float*)d_in[0];
  const float* w_qkv = (const float*)d_in[1];
  const float* w_out = (const float*)d_in[2];
  const float* fcos = (const float*)d_in[3];
  const float* fsin = (const float*)d_in[4];
  float* out = (float*)d_out;

  char* ws = (char*)d_ws;
  ushort_t* x_bf    = (ushort_t*)(ws + 0);
  ushort_t* wqkv_bf = (ushort_t*)(ws + 16777216);
  ushort_t* wout_bf = (ushort_t*)(ws + 41943040);
  ushort_t* qkv     = (ushort_t*)(ws + 50331648);
  ushort_t* attn    = (ushort_t*)(ws + 100663296);
  float* Oacc   = (float*)(ws + 0);            // aliases x_bf/wqkv_bf (dead)
  float* lsum_g = (float*)(ws + 33554432);
  ushort_t* VTg = (ushort_t*)(ws + 100663296); // aliases attn (disjoint lifetime)

  // zero the fp32 output accumulator for gemm2 split-K atomics
  hipMemsetAsync(out, 0, 33554432, stream);

  cvt_all<<<24576, 256, 0, stream>>>(x, w_qkv, w_out, x_bf);

  // qkv = x @ w_qkv^T (M=4096,N=6144,K=2048), RoPE fused into epilogue
  gemm_bt<ushort_t, false, true><<<dim3(48, 32, 1), 256, 0, stream>>>(
      x_bf, wqkv_bf, qkv, 4096, 6144, 2048, 2048, fcos, fsin);

  vt_prep<<<dim3(32, 16, 2), 256, 0, stream>>>(qkv, VTg);

  hipMemsetAsync(Oacc, 0, 33554432, stream);
  hipMemsetAsync(lsum_g, 0, 262144, stream);

  attn_fwd<<<dim3(80, 16, 2), 256, 0, stream>>>(qkv, VTg, Oacc, lsum_g);
  combine<<<8192, 256, 0, stream>>>(Oacc, lsum_g, attn);

  // out = attn @ w_out^T (M=4096,N=2048,K=2048), split-K=2, fp32 atomic out
  gemm_bt<float, true, false><<<dim3(16, 32, 2), 256, 0, stream>>>(
      attn, wout_bf, out, 4096, 2048, 2048, 1024, nullptr, nullptr);
}

// Round 6
// 498.434 us; speedup vs baseline: 1.0418x; 1.0349x over previous
//
#include <hip/hip_runtime.h>
#include <hip/hip_bf16.h>
#include <stdint.h>

// Problem: B=2, S=2048, D=2048, H=16, HD=128
#define S_ 2048
#define D_ 2048
#define H_ 16
#define HD_ 128

typedef __bf16 bf16x8 __attribute__((ext_vector_type(8)));
typedef float f32x4 __attribute__((ext_vector_type(4)));
typedef unsigned short ushort_t;
typedef ushort_t us4 __attribute__((ext_vector_type(4)));

__device__ __forceinline__ float bf2f(ushort_t u) {
  union { float f; uint32_t i; } x; x.i = ((uint32_t)u) << 16; return x.f;
}
__device__ __forceinline__ ushort_t f2bf(float f) {
  union { float f; uint32_t i; } x; x.f = f;
  uint32_t r = x.i + 0x7fffu + ((x.i >> 16) & 1u);  // RNE
  return (ushort_t)(r >> 16);
}

// async global->LDS, 16B per lane. LDS dest is wave-uniform base + lane*16.
__device__ __forceinline__ void async_copy16(const void* g, void* l) {
  __builtin_amdgcn_global_load_lds(
      (const __attribute__((address_space(1))) unsigned int*)g,
      (__attribute__((address_space(3))) unsigned int*)l, 16, 0, 0);
}

__device__ __forceinline__ void store_val(float* p, float v) { *p = v; }
__device__ __forceinline__ void store_val(ushort_t* p, float v) { *p = f2bf(v); }

// ---------------- fp32 -> bf16 convert, all three tensors in one launch -----
__global__ __launch_bounds__(256) void cvt_all(const float* __restrict__ x,
                                               const float* __restrict__ wqkv,
                                               const float* __restrict__ wout,
                                               ushort_t* __restrict__ dst) {
  int i = blockIdx.x * 256 + threadIdx.x;  // [0, 6291456)
  const float4 v = (i < 2097152) ? ((const float4*)x)[i]
                 : (i < 5242880) ? ((const float4*)wqkv)[i - 2097152]
                                 : ((const float4*)wout)[i - 5242880];
  us4 o;
  o.x = f2bf(v.x); o.y = f2bf(v.y); o.z = f2bf(v.z); o.w = f2bf(v.w);
  ((us4*)dst)[i] = o;
}

// ---------------- GEMM: C[M,N] = A[M,K] * B[N,K]^T  (bf16, fp32 acc) --------
// Exact R3 structure (known 141 us / 729 TF on the QKV shape): 128x128 tile,
// BK=32, 4 waves 2x2, global_load_lds w=16, plain-store or atomic epilogue.
// NOTE: SQ_LDS_BANK_CONFLICT ~1.26e7 here is global_load_lds DMA-write
// serialization - constant across staging variants, not read-conflicts (R4/R5).
template <typename OutT, bool ATOMIC>
__global__ __launch_bounds__(256) void gemm_bt(const ushort_t* __restrict__ A,
                                               const ushort_t* __restrict__ Bm,
                                               OutT* __restrict__ C,
                                               int M, int N, int K, int ksplit) {
  __shared__ __align__(16) ushort_t As[128 * 32];
  __shared__ __align__(16) ushort_t Bs[128 * 32];
  const int tid = threadIdx.x;
  const int wave = tid >> 6, lane = tid & 63;
  const int quad = lane >> 4, l16 = lane & 15;
  const int bm = blockIdx.y * 128, bn = blockIdx.x * 128;
  const int wm = (wave >> 1) * 64, wn = (wave & 1) * 64;
  const int kbeg = blockIdx.z * ksplit, kend = kbeg + ksplit;

  f32x4 acc[4][4] = {};

  const int c0 = wave * 2, c1 = c0 + 1;
  const int srow = lane >> 2;
  const int scol = (lane & 3) * 8;
  const ushort_t* gA0 = A + (size_t)(bm + c0 * 16 + srow) * K + scol;
  const ushort_t* gA1 = A + (size_t)(bm + c1 * 16 + srow) * K + scol;
  const ushort_t* gB0 = Bm + (size_t)(bn + c0 * 16 + srow) * K + scol;
  const ushort_t* gB1 = Bm + (size_t)(bn + c1 * 16 + srow) * K + scol;
  ushort_t* lA0 = As + c0 * 512;
  ushort_t* lA1 = As + c1 * 512;
  ushort_t* lB0 = Bs + c0 * 512;
  ushort_t* lB1 = Bs + c1 * 512;

  for (int k0 = kbeg; k0 < kend; k0 += 32) {
    __syncthreads();
    async_copy16(gA0 + k0, lA0);
    async_copy16(gA1 + k0, lA1);
    async_copy16(gB0 + k0, lB0);
    async_copy16(gB1 + k0, lB1);
    __syncthreads();
    bf16x8 af[4], bfr[4];
#pragma unroll
    for (int i = 0; i < 4; ++i)
      af[i] = *(const bf16x8*)(As + (wm + i * 16 + l16) * 32 + quad * 8);
#pragma unroll
    for (int i = 0; i < 4; ++i)
      bfr[i] = *(const bf16x8*)(Bs + (wn + i * 16 + l16) * 32 + quad * 8);
#pragma unroll
    for (int mi = 0; mi < 4; ++mi)
#pragma unroll
      for (int ni = 0; ni < 4; ++ni)
        acc[mi][ni] = __builtin_amdgcn_mfma_f32_16x16x32_bf16(af[mi], bfr[ni],
                                                              acc[mi][ni], 0, 0, 0);
  }
#pragma unroll
  for (int mi = 0; mi < 4; ++mi)
#pragma unroll
    for (int ni = 0; ni < 4; ++ni)
#pragma unroll
      for (int r = 0; r < 4; ++r) {
        int row = bm + wm + mi * 16 + quad * 4 + r;
        int col = bn + wn + ni * 16 + l16;
        if constexpr (ATOMIC)
          unsafeAtomicAdd((float*)&C[(size_t)row * N + col], acc[mi][ni][r]);
        else
          store_val(&C[(size_t)row * N + col], acc[mi][ni][r]);
      }
}

// ---------------- RoPE in-place on q and k halves of qkv ----------------
__global__ __launch_bounds__(256) void rope_k(ushort_t* __restrict__ qkv,
                                              const float* __restrict__ fc,
                                              const float* __restrict__ fs) {
  int idx = blockIdx.x * 256 + threadIdx.x;
  int i = idx & 63;
  int hh = (idx >> 6) & 15;
  int m = idx >> 10;
  int s = m & (S_ - 1);
  float c = fc[s * 64 + i], sn = fs[s * 64 + i];
  size_t off = (size_t)m * (3 * D_) + hh * HD_ + 2 * i;
#pragma unroll
  for (int part = 0; part < 2; ++part) {
    uint32_t* p = (uint32_t*)(qkv + off + part * D_);
    uint32_t v = *p;
    float re = bf2f((ushort_t)(v & 0xffffu));
    float im = bf2f((ushort_t)(v >> 16));
    float nr = re * c - im * sn;
    float ni = re * sn + im * c;
    *p = (uint32_t)f2bf(nr) | ((uint32_t)f2bf(ni) << 16);
  }
}

// ---------------- V transpose: qkv V part -> VTg[(b*H+h)*HD + d][S] ---------
__global__ __launch_bounds__(256) void vt_prep(const ushort_t* __restrict__ qkv,
                                               ushort_t* __restrict__ VTg) {
  __shared__ __align__(16) ushort_t T[64 * 136];
  const int st = blockIdx.x, h = blockIdx.y, b = blockIdx.z;
  const int tid = threadIdx.x;
  const ushort_t* gV = qkv + (size_t)(b * S_ + st * 64) * (3 * D_) + 2 * D_ + h * HD_;
  {
    const int r = tid >> 2, cc = (tid & 3) * 32;
    const ushort_t* src = gV + (size_t)r * (3 * D_) + cc;
    uint4 a0 = ((const uint4*)src)[0];
    uint4 a1 = ((const uint4*)src)[1];
    uint4 a2 = ((const uint4*)src)[2];
    uint4 a3 = ((const uint4*)src)[3];
    ushort_t* dst = T + r * 136 + cc;
    ((uint4*)dst)[0] = a0; ((uint4*)dst)[1] = a1;
    ((uint4*)dst)[2] = a2; ((uint4*)dst)[3] = a3;
  }
  __syncthreads();
  const int d = tid >> 1, kh = (tid & 1) * 32;
  ushort_t buf[32];
#pragma unroll
  for (int j = 0; j < 32; ++j) buf[j] = T[(kh + j) * 136 + d];
  ushort_t* out = VTg + ((size_t)((b * H_ + h) * HD_ + d)) * S_ + st * 64 + kh;
  ((uint4*)out)[0] = *(const uint4*)(buf + 0);
  ((uint4*)out)[1] = *(const uint4*)(buf + 8);
  ((uint4*)out)[2] = *(const uint4*)(buf + 16);
  ((uint4*)out)[3] = *(const uint4*)(buf + 24);
}

// ---------------- Flash attention v3: key-split chunks, async staging -------
#define SOFTMAX_C 12.0f

__global__ __launch_bounds__(256, 4) void attn_fwd(const ushort_t* __restrict__ qkv,
                                                   const ushort_t* __restrict__ VTg,
                                                   float* __restrict__ Oacc,
                                                   float* __restrict__ lsum_g) {
  __shared__ __align__(16) ushort_t Kl[64 * 128];   // [key][d]   16 KB
  __shared__ __align__(16) ushort_t VT[128 * 64];   // [d][key]   16 KB
  __shared__ __align__(16) ushort_t Pl[4 * 16 * 64];// per-wave P  8 KB

  const int j = 79 - (int)blockIdx.x;
  int qt, c;
  if (j < 8)       { qt = j;                 c = 0; }
  else if (j < 24) { int t = j - 8;  qt = 8 + (t >> 1);  c = t & 1; }
  else if (j < 48) { int t = j - 24; qt = 16 + t / 3;    c = t % 3; }
  else             { int t = j - 48; qt = 24 + (t >> 2); c = t & 3; }
  const int h = blockIdx.y, b = blockIdx.z;
  const int kt0 = c * 8;
  const int kt_end = min(kt0 + 8, qt + 1);

  const int tid = threadIdx.x;
  const int wave = tid >> 6, lane = tid & 63;
  const int quad = lane >> 4, l16 = lane & 15;
  const float scale = 0.08838834764831845f;  // 1/sqrt(128)

  const int qg = qt * 64 + wave * 16 + l16;
  const ushort_t* qrow = qkv + (size_t)(b * S_ + qg) * (3 * D_) + h * HD_;
  bf16x8 qf[4];
#pragma unroll
  for (int cc = 0; cc < 4; ++cc)
    qf[cc] = *(const bf16x8*)(qrow + cc * 32 + quad * 8);

  f32x4 o[8] = {};
  float lsum[4] = {0.f, 0.f, 0.f, 0.f};
  const int q_row_base = qt * 64 + wave * 16 + quad * 4;
  ushort_t* Pw = Pl + wave * 16 * 64;

  const ushort_t* gK = qkv + (size_t)(b * S_) * (3 * D_) + D_ + h * HD_;
  const ushort_t* gVT = VTg + (size_t)(b * H_ + h) * HD_ * S_;

  const int krow_off = lane >> 4;
  const int kchunk = lane & 15;
  const int vrow_off = lane >> 3;
  const int vchunk = lane & 7;

  for (int kt = kt0; kt < kt_end; ++kt) {
    __syncthreads();
#pragma unroll
    for (int i = 0; i < 4; ++i) {
      int row = wave * 16 + i * 4 + krow_off;
      int lchunk = kchunk ^ (row & 15);
      async_copy16(gK + (size_t)(kt * 64 + row) * (3 * D_) + lchunk * 8,
                   Kl + (wave * 16 + i * 4) * 128);
    }
#pragma unroll
    for (int i = 0; i < 4; ++i) {
      int row = wave * 32 + i * 8 + vrow_off;
      int lchunk = vchunk ^ (row & 7);
      async_copy16(gVT + (size_t)row * S_ + kt * 64 + lchunk * 8,
                   VT + (wave * 32 + i * 8) * 64);
    }
    __syncthreads();

    const bool diag = (kt == qt);
#pragma unroll
    for (int g = 0; g < 4; ++g) {
      f32x4 s = {0.f, 0.f, 0.f, 0.f};
#pragma unroll
      for (int cc = 0; cc < 4; ++cc) {
        bf16x8 kf = *(const bf16x8*)(Kl + (g * 16 + l16) * 128 +
                                     (((cc * 4 + quad) ^ l16) * 8));
        s = __builtin_amdgcn_mfma_f32_16x16x32_bf16(qf[cc], kf, s, 0, 0, 0);
      }
      const int key = kt * 64 + g * 16 + l16;
#pragma unroll
      for (int r = 0; r < 4; ++r) {
        float e = __expf(s[r] * scale - SOFTMAX_C);
        float p = (!diag || key <= q_row_base + r) ? e : 0.f;
        lsum[r] += p;
        int prow = quad * 4 + r;
        int pcol = g * 16 + l16;
        Pw[prow * 64 + (((pcol >> 3) ^ (prow & 7)) * 8) + (pcol & 7)] = f2bf(p);
      }
    }
    bf16x8 pf0 = *(const bf16x8*)(Pw + l16 * 64 + ((quad ^ (l16 & 7)) * 8));
    bf16x8 pf1 = *(const bf16x8*)(Pw + l16 * 64 + (((4 + quad) ^ (l16 & 7)) * 8));
#pragma unroll
    for (int dc = 0; dc < 8; ++dc) {
      bf16x8 v0 = *(const bf16x8*)(VT + (dc * 16 + l16) * 64 +
                                   (((0 * 4 + quad) ^ (l16 & 7)) * 8));
      o[dc] = __builtin_amdgcn_mfma_f32_16x16x32_bf16(pf0, v0, o[dc], 0, 0, 0);
      bf16x8 v1 = *(const bf16x8*)(VT + (dc * 16 + l16) * 64 +
                                   (((1 * 4 + quad) ^ (l16 & 7)) * 8));
      o[dc] = __builtin_amdgcn_mfma_f32_16x16x32_bf16(pf1, v1, o[dc], 0, 0, 0);
    }
  }

#pragma unroll
  for (int r = 0; r < 4; ++r) {
    float l = lsum[r];
    l += __shfl_xor(l, 1, 64);
    l += __shfl_xor(l, 2, 64);
    l += __shfl_xor(l, 4, 64);
    l += __shfl_xor(l, 8, 64);
    size_t row = (size_t)(b * S_ + q_row_base + r);
    if (l16 == 0) unsafeAtomicAdd(&lsum_g[row * H_ + h], l);
#pragma unroll
    for (int dc = 0; dc < 8; ++dc)
      unsafeAtomicAdd(&Oacc[row * D_ + h * HD_ + dc * 16 + l16], o[dc][r]);
  }
}

// ---------------- combine: normalize O by lsum, emit bf16 -------------------
__global__ __launch_bounds__(256) void combine(const float* __restrict__ Oacc,
                                               const float* __restrict__ lsum_g,
                                               ushort_t* __restrict__ attn) {
  int i = blockIdx.x * 256 + threadIdx.x;
  float4 v = ((const float4*)Oacc)[i];
  int flat = i * 4;
  int row = flat >> 11;
  int h = (flat >> 7) & 15;
  float inv = 1.0f / lsum_g[row * H_ + h];
  us4 o;
  o.x = f2bf(v.x * inv); o.y = f2bf(v.y * inv);
  o.z = f2bf(v.z * inv); o.w = f2bf(v.w * inv);
  ((us4*)attn)[i] = o;
}

// ---------------- launch ----------------
extern "C" void kernel_launch(void* const* d_in, const int* in_sizes, int n_in,
                              void* d_out, int out_size, void* d_ws, size_t ws_size,
                              hipStream_t stream) {
  const float* x = (const float*)d_in[0];
  const float* w_qkv = (const float*)d_in[1];
  const float* w_out = (const float*)d_in[2];
  const float* fcos = (const float*)d_in[3];
  const float* fsin = (const float*)d_in[4];
  float* out = (float*)d_out;

  char* ws = (char*)d_ws;
  ushort_t* x_bf    = (ushort_t*)(ws + 0);
  ushort_t* wqkv_bf = (ushort_t*)(ws + 16777216);
  ushort_t* wout_bf = (ushort_t*)(ws + 41943040);
  ushort_t* qkv     = (ushort_t*)(ws + 50331648);
  ushort_t* attn    = (ushort_t*)(ws + 100663296);
  float* Oacc   = (float*)(ws + 0);            // aliases x_bf/wqkv_bf (dead)
  float* lsum_g = (float*)(ws + 33554432);
  ushort_t* VTg = (ushort_t*)(ws + 100663296); // aliases attn (disjoint lifetime)

  // zero the fp32 output for gemm2 split-K atomics (d_out is poisoned)
  hipMemsetAsync(out, 0, 33554432, stream);

  cvt_all<<<24576, 256, 0, stream>>>(x, w_qkv, w_out, x_bf);

  // qkv = x @ w_qkv^T : M=4096, N=6144, K=2048
  gemm_bt<ushort_t, false><<<dim3(48, 32, 1), 256, 0, stream>>>(
      x_bf, wqkv_bf, qkv, 4096, 6144, 2048, 2048);

  rope_k<<<16384, 256, 0, stream>>>(qkv, fcos, fsin);
  vt_prep<<<dim3(32, 16, 2), 256, 0, stream>>>(qkv, VTg);

  hipMemsetAsync(Oacc, 0, 33554432, stream);
  hipMemsetAsync(lsum_g, 0, 262144, stream);

  attn_fwd<<<dim3(80, 16, 2), 256, 0, stream>>>(qkv, VTg, Oacc, lsum_g);
  combine<<<8192, 256, 0, stream>>>(Oacc, lsum_g, attn);

  // out = attn @ w_out^T : M=4096, N=2048, K=2048, split-K=2, fp32 atomic out
  gemm_bt<float, true><<<dim3(16, 32, 2), 256, 0, stream>>>(
      attn, wout_bf, out, 4096, 2048, 2048, 1024);
}